// Round 9
// baseline (85.124 us; speedup 1.0000x reference)
//
#include <hip/hip_runtime.h>
#include <math.h>

// ---------------------------------------------------------------------------
// LorentzSelfAttention — MI355X
//
// Degenerate-clamp simplification (verified analytically, passed R1-R8):
//   u_agg_i = C*(W_i + S_i*Q_i),  W_i = sum_j p_ij V_j (unnormalized),
//   S_i = sum_j p_ij alpha_ij = -mink(Q_i, W_i)   [alpha bilinear in V]
//   Y_i = mink_normalize(Q_i + u_agg_i/sum_e), |time|
//   Ztan_i = dist0*C * (2*Y0, Ys),  dist0 = acosh(max(Y0,1+eps))
//
// R9: attn occupancy: 4 rows/block, grid (128,16)=2048 blocks (8/CU, 32
// waves/CU), j-pair/thread float2 loads; S_i via Minkowski identity in P5
// (per-pair sa accumulation deleted). QKV split-K x4 (1536 blocks, 6/CU).
// ---------------------------------------------------------------------------

namespace {

constexpr int Tq = 512;
constexpr int QS = 36;            // padded Q row stride
constexpr int ZPHALF = 786432;    // 1024*768

#define EPSF  1e-6f
#define CINV  3.16227766e7f       // 1/sqrt(1e-15)

__device__ __forceinline__ float facosh(float x) {
    // caller guarantees x >= 1+1e-6
    return __logf(x + __builtin_amdgcn_sqrtf(fmaf(x, x, -1.0f)));
}

// ---------------- Kernel 1: QKV GEMM, split-K x4, 32x64 tiles --------------
__global__ __launch_bounds__(256) void gemm_qkv_split_kernel(
    const float* __restrict__ x,
    const float* __restrict__ Wq, const float* __restrict__ Wk,
    const float* __restrict__ Wv, float* __restrict__ zpart)
{
    __shared__ float AsT[32][36];     // k-major
    __shared__ float BsT[32][68];

    const int n0 = blockIdx.x * 64;   // 0..704
    const int m0 = blockIdx.y * 32;   // 0..992
    const int kz = blockIdx.z;        // 0..3
    const int t  = threadIdx.x;
    const int tx = t & 15, ty = t >> 4;

    float acc[2][4];
    #pragma unroll
    for (int r = 0; r < 2; ++r)
        #pragma unroll
        for (int c = 0; c < 4; ++c) acc[r][c] = 0.f;

    const int ob  = n0 + (t >> 2);    // B row staged by this thread
    const float* WselB = (ob < 256) ? Wq : (ob < 512 ? Wk : Wv);
    const int obr = ob & 255;
    const int ar  = t >> 3;           // A row 0..31
    const int ac  = (t & 7) * 4;      // k 0..28
    const int bcc = (t & 3) * 8;      // k 0,8,16,24
    const int bcol = t >> 2;          // 0..63

    const int kbeg = kz * 128;
    for (int k0 = kbeg; k0 < kbeg + 128; k0 += 32) {
        const float4 av = *reinterpret_cast<const float4*>(&x[(m0 + ar) * 512 + k0 + ac]);
        AsT[ac + 0][ar] = av.x; AsT[ac + 1][ar] = av.y;
        AsT[ac + 2][ar] = av.z; AsT[ac + 3][ar] = av.w;
        const float4 b0 = *reinterpret_cast<const float4*>(&WselB[obr * 512 + k0 + bcc]);
        const float4 b1 = *reinterpret_cast<const float4*>(&WselB[obr * 512 + k0 + bcc + 4]);
        BsT[bcc + 0][bcol] = b0.x; BsT[bcc + 1][bcol] = b0.y;
        BsT[bcc + 2][bcol] = b0.z; BsT[bcc + 3][bcol] = b0.w;
        BsT[bcc + 4][bcol] = b1.x; BsT[bcc + 5][bcol] = b1.y;
        BsT[bcc + 6][bcol] = b1.z; BsT[bcc + 7][bcol] = b1.w;
        __syncthreads();
        #pragma unroll
        for (int kk = 0; kk < 32; ++kk) {
            const float2 a2 = *reinterpret_cast<const float2*>(&AsT[kk][ty * 2]);
            const float4 b4 = *reinterpret_cast<const float4*>(&BsT[kk][tx * 4]);
            const float ar2[2] = {a2.x, a2.y};
            const float br4[4] = {b4.x, b4.y, b4.z, b4.w};
            #pragma unroll
            for (int r = 0; r < 2; ++r)
                #pragma unroll
                for (int c = 0; c < 4; ++c) acc[r][c] = fmaf(ar2[r], br4[c], acc[r][c]);
        }
        __syncthreads();
    }
    float* zp = zpart + kz * ZPHALF + (m0 + ty * 2) * 768 + n0 + tx * 4;
    #pragma unroll
    for (int r = 0; r < 2; ++r) {
        float4 o; o.x = acc[r][0]; o.y = acc[r][1]; o.z = acc[r][2]; o.w = acc[r][3];
        *reinterpret_cast<float4*>(zp + r * 768) = o;
    }
}

// ---------------- Kernel 2: reduce 4 k-parts + bias + FL lift --------------
__global__ __launch_bounds__(256) void reduce_fl_kernel(
    const float* __restrict__ zpart,
    const float* __restrict__ bq, const float* __restrict__ bk,
    const float* __restrict__ bv,
    float* __restrict__ Q, float* __restrict__ K, float* __restrict__ V)
{
    const int u = blockIdx.x * 256 + threadIdx.x;   // < 24576
    const int tt = u & 511;
    const int rest = u >> 9;          // 0..47
    const int bh = rest & 15;
    const int which = rest >> 4;      // 0=q 1=k 2=v
    const int b = bh >> 3, h = bh & 7;
    const int row = b * 512 + tt;
    const int col = which * 256 + h * 32;
    const float* z0 = zpart + row * 768 + col;
    const float* bsel = (which == 0) ? bq : (which == 1 ? bk : bv);

    float zv[32];
    float s2 = 0.f;
    #pragma unroll
    for (int c = 0; c < 8; ++c) {
        const float4 a0 = *reinterpret_cast<const float4*>(&z0[c * 4]);
        const float4 a1 = *reinterpret_cast<const float4*>(&z0[ZPHALF + c * 4]);
        const float4 a2 = *reinterpret_cast<const float4*>(&z0[2 * ZPHALF + c * 4]);
        const float4 a3 = *reinterpret_cast<const float4*>(&z0[3 * ZPHALF + c * 4]);
        const float4 bb = *reinterpret_cast<const float4*>(&bsel[h * 32 + c * 4]);
        zv[c*4+0] = ((a0.x + a1.x) + (a2.x + a3.x)) + bb.x;
        zv[c*4+1] = ((a0.y + a1.y) + (a2.y + a3.y)) + bb.y;
        zv[c*4+2] = ((a0.z + a1.z) + (a2.z + a3.z)) + bb.z;
        zv[c*4+3] = ((a0.w + a1.w) + (a2.w + a3.w)) + bb.w;
    }
    #pragma unroll
    for (int k = 0; k < 32; ++k) s2 = fmaf(zv[k], zv[k], s2);

    const float rr = __builtin_amdgcn_sqrtf(s2);
    const float rs = fminf(fmaxf(rr, 1e-12f), 18.0f);
    const float e  = __expf(rs);
    const float ei = __builtin_amdgcn_rcpf(e);
    const float ch = 0.5f * (e + ei);
    float sc = 0.5f * (e - ei) / rs;
    if (rs < 1e-3f) sc = fmaf(rs * rs, 1.0f / 6.0f, 1.0f);
    float y0 = ch;
    float ys[32];
    float mink = -y0 * y0;
    #pragma unroll
    for (int k = 0; k < 32; ++k) { ys[k] = sc * zv[k]; mink = fmaf(ys[k], ys[k], mink); }
    const float inv = __builtin_amdgcn_rsqf(fmaxf(fabsf(mink), 1e-15f));
    y0 = fabsf(y0 * inv);

    if (which == 0) {
        float* qp = Q + (bh * Tq + tt) * QS;
        #pragma unroll
        for (int k = 0; k < 32; ++k) qp[k] = ys[k] * inv;
        qp[32] = y0; qp[33] = 0.f; qp[34] = 0.f; qp[35] = 0.f;
    } else {
        float* p = ((which == 1) ? K : V) + bh * 33 * Tq + tt;
        p[0] = y0;
        #pragma unroll
        for (int k = 0; k < 32; ++k) p[(k + 1) * Tq] = ys[k] * inv;
    }
}

// ---------------- Kernel 3: attention, 4 rows/block, grid (128,16) ---------
// 256 threads; thread t owns columns {2t, 2t+1} in P1 (float2 loads).
__global__ __launch_bounds__(256) void attn_kernel(
    const float* __restrict__ Q, const float* __restrict__ K,
    const float* __restrict__ V, float* __restrict__ Ztan)
{
    __shared__ float sQ[4][36];       // [0..31]=spatial, [32]=time
    __shared__ float sBig[4 * 512];   // p matrix; P4 partials alias
    __shared__ float sSe[4][4];       // per-wave sum_e partials
    __shared__ float sW[4][33];

    float (*sP)[512] = reinterpret_cast<float(*)[512]>(sBig);
    float (*part)[8][20] = reinterpret_cast<float(*)[8][20]>(sBig); // [g][sub][20]

    const int bh = blockIdx.y;
    const int i0 = blockIdx.x * 4;
    const int t  = threadIdx.x;       // 0..255
    const int lane = t & 63, wv = t >> 6;

    const float* Qb = Q + (bh * Tq + i0) * QS;
    const float* Kb = K + bh * 33 * Tq;
    const float* Vb = V + bh * 33 * Tq;

    if (t < 4 * QS) sQ[t / QS][t % QS] = Qb[t];   // 144 <= 256
    __syncthreads();

    // ---- P1: p = exp(-d^2)*dd into LDS; row sum_e in regs -----------------
    float se[4];
    #pragma unroll
    for (int i = 0; i < 4; ++i) se[i] = 0.f;
    {
        const int j0 = 2 * t;
        float aK[4][2], aV[4][2];
        #pragma unroll
        for (int i = 0; i < 4; ++i) {
            aK[i][0] = aK[i][1] = 0.f; aV[i][0] = aV[i][1] = 0.f;
        }
        #pragma unroll 2
        for (int ch = 0; ch < 4; ++ch) {
            float2 ks[8], vs[8];
            #pragma unroll
            for (int k = 0; k < 8; ++k) {
                ks[k] = *reinterpret_cast<const float2*>(&Kb[(ch * 8 + k + 1) * Tq + j0]);
                vs[k] = *reinterpret_cast<const float2*>(&Vb[(ch * 8 + k + 1) * Tq + j0]);
            }
            #pragma unroll
            for (int i = 0; i < 4; ++i) {
                const float4 qa = *reinterpret_cast<const float4*>(&sQ[i][ch * 8]);
                const float4 qb = *reinterpret_cast<const float4*>(&sQ[i][ch * 8 + 4]);
                const float qv[8] = {qa.x, qa.y, qa.z, qa.w, qb.x, qb.y, qb.z, qb.w};
                float k0a = aK[i][0], k1a = aK[i][1], v0a = aV[i][0], v1a = aV[i][1];
                #pragma unroll
                for (int k = 0; k < 8; ++k) {
                    k0a = fmaf(qv[k], ks[k].x, k0a);
                    k1a = fmaf(qv[k], ks[k].y, k1a);
                    v0a = fmaf(qv[k], vs[k].x, v0a);
                    v1a = fmaf(qv[k], vs[k].y, v1a);
                }
                aK[i][0] = k0a; aK[i][1] = k1a; aV[i][0] = v0a; aV[i][1] = v1a;
            }
        }
        const float2 k0v = *reinterpret_cast<const float2*>(&Kb[j0]);
        const float2 v0v = *reinterpret_cast<const float2*>(&Vb[j0]);
        #pragma unroll
        for (int i = 0; i < 4; ++i) {
            const float q0 = sQ[i][32];
            const float ip0 = fmaf(q0, k0v.x, -aK[i][0]);
            const float ip1 = fmaf(q0, k0v.y, -aK[i][1]);
            const float d0 = facosh(fmaxf(ip0, 1.0f + EPSF));
            const float d1 = facosh(fmaxf(ip1, 1.0f + EPSF));
            const float al0 = fmaxf(fmaf(q0, v0v.x, -aV[i][0]), 1.0f + EPSF);
            const float al1 = fmaxf(fmaf(q0, v0v.y, -aV[i][1]), 1.0f + EPSF);
            const float e0 = __expf(-d0 * d0);
            const float e1 = __expf(-d1 * d1);
            float2 p; p.x = e0 * facosh(al0); p.y = e1 * facosh(al1);
            *reinterpret_cast<float2*>(&sP[i][j0]) = p;
            se[i] += e0 + e1;
        }
    }
    #pragma unroll
    for (int i = 0; i < 4; ++i) {
        float a = se[i];
        #pragma unroll
        for (int off = 32; off > 0; off >>= 1) a += __shfl_xor(a, off, 64);
        if (lane == 0) sSe[i][wv] = a;
    }
    __syncthreads();

    // ---- P4: Wraw[i][a] = sum_j p_ij * V[a][j] ----------------------------
    // 8 groups of 32 lanes: group g covers a = g*4 .. g*4+4 (5 wide), all 4 rows.
    {
        const int jl = t & 31, g = t >> 5;
        const int abase = g * 4;          // 0..28; +4 = 32 max, in range
        float acc[4][5];
        #pragma unroll
        for (int il = 0; il < 4; ++il)
            #pragma unroll
            for (int al = 0; al < 5; ++al) acc[il][al] = 0.f;

        #pragma unroll 1
        for (int it = 0; it < 8; ++it) {
            const int jb = it * 64 + jl * 2;
            float2 v2[5];
            #pragma unroll
            for (int al = 0; al < 5; ++al)
                v2[al] = *reinterpret_cast<const float2*>(&Vb[(abase + al) * Tq + jb]);
            #pragma unroll
            for (int il = 0; il < 4; ++il) {
                const float2 w2 = *reinterpret_cast<const float2*>(&sP[il][jb]);
                #pragma unroll
                for (int al = 0; al < 5; ++al)
                    acc[il][al] = fmaf(w2.y, v2[al].y, fmaf(w2.x, v2[al].x, acc[il][al]));
            }
        }
        #pragma unroll
        for (int il = 0; il < 4; ++il)
            #pragma unroll
            for (int al = 0; al < 5; ++al) {
                float v = acc[il][al];
                v += __shfl_xor(v, 1, 64);
                v += __shfl_xor(v, 2, 64);
                acc[il][al] = v;
            }
        __syncthreads();   // all sP reads complete before part overwrites
        if ((jl & 3) == 0) {
            const int sub = jl >> 2;
            #pragma unroll
            for (int il = 0; il < 4; ++il)
                #pragma unroll
                for (int al = 0; al < 5; ++al)
                    part[g][sub][il * 5 + al] = acc[il][al];
        }
    }
    __syncthreads();

    // ---- stage 2: fold 8 partials per (i,a) -------------------------------
    if (t < 4 * 33) {
        const int i = t / 33, a = t - i * 33;
        int g2, al;
        if (a < 28) { g2 = a >> 2; al = a & 3; } else { g2 = 7; al = a - 28; }
        const int idx = i * 5 + al;
        float s = 0.f;
        #pragma unroll
        for (int sub = 0; sub < 8; ++sub) s += part[g2][sub][idx];
        sW[i][a] = s;
    }
    __syncthreads();

    // ---- P5: S via Minkowski identity; normalize; exp_map; origin log -----
    if (t < 4) {
        const int i = t;
        const float seT = sSe[i][0] + sSe[i][1] + sSe[i][2] + sSe[i][3];
        const float q0 = sQ[i][32];
        // S_raw = -mink(Q, Wraw) = q0*W0 - sum_s qs*Ws
        float dot = 0.f;
        #pragma unroll
        for (int a = 1; a < 33; ++a) dot = fmaf(sQ[i][a - 1], sW[i][a], dot);
        const float S = q0 * sW[i][0] - dot;
        const float cs = CINV * __builtin_amdgcn_rcpf(seT);
        const float y0 = fmaf(cs, fmaf(S, q0, sW[i][0]), q0);
        float mink = -y0 * y0;
        float yv[32];
        #pragma unroll
        for (int a = 1; a < 33; ++a) {
            const float qa = sQ[i][a - 1];
            const float ya = fmaf(cs, fmaf(S, qa, sW[i][a]), qa);
            yv[a - 1] = ya;
            mink = fmaf(ya, ya, mink);
        }
        const float inv = __builtin_amdgcn_rsqf(fmaxf(fabsf(mink), 1e-15f));
        const float Y0 = fabsf(y0 * inv);
        const float dist0 = facosh(fmaxf(Y0, 1.0f + EPSF));
        const float coef = dist0 * CINV;
        const int b = bh >> 3, h = bh & 7;
        float* zp = Ztan + ((b * Tq + (i0 + i)) * 264) + h * 33;
        zp[0] = coef * (2.0f * Y0);
        #pragma unroll
        for (int a = 1; a < 33; ++a) zp[a] = coef * (yv[a - 1] * inv);
    }
}

// ---------------- Kernel 4: Z = Ztan(1024x264) @ Wo^T + bo, 32x32 tiles ----
__global__ __launch_bounds__(256) void out_gemm_kernel(
    const float* __restrict__ Ztan, const float* __restrict__ Wo,
    const float* __restrict__ bo, float* __restrict__ out)
{
    __shared__ float AsT[8][36];
    __shared__ float BsT[8][36];
    const int n0 = blockIdx.x * 32;
    const int m0 = blockIdx.y * 32;
    const int t  = threadIdx.x;
    const int tx = t & 15, ty = t >> 4;
    const int ar = t >> 3, ac = t & 7;

    float acc[2][2];
    acc[0][0] = acc[0][1] = acc[1][0] = acc[1][1] = 0.f;

    for (int k0 = 0; k0 < 264; k0 += 8) {
        AsT[ac][ar] = Ztan[(m0 + ar) * 264 + k0 + ac];
        BsT[ac][ar] = Wo[(n0 + ar) * 264 + k0 + ac];
        __syncthreads();
        #pragma unroll
        for (int kk = 0; kk < 8; ++kk) {
            const float2 a2 = *reinterpret_cast<const float2*>(&AsT[kk][ty * 2]);
            const float2 b2 = *reinterpret_cast<const float2*>(&BsT[kk][tx * 2]);
            acc[0][0] = fmaf(a2.x, b2.x, acc[0][0]);
            acc[0][1] = fmaf(a2.x, b2.y, acc[0][1]);
            acc[1][0] = fmaf(a2.y, b2.x, acc[1][0]);
            acc[1][1] = fmaf(a2.y, b2.y, acc[1][1]);
        }
        __syncthreads();
    }
    #pragma unroll
    for (int c = 0; c < 2; ++c) {
        const int o = n0 + tx * 2 + c;
        const float bias = bo[o];
        #pragma unroll
        for (int r = 0; r < 2; ++r)
            out[(m0 + ty * 2 + r) * 512 + o] = acc[r][c] + bias;
    }
}

} // namespace

// ---------------------------------------------------------------------------
extern "C" void kernel_launch(void* const* d_in, const int* in_sizes, int n_in,
                              void* d_out, int out_size, void* d_ws, size_t ws_size,
                              hipStream_t stream)
{
    const float* x  = (const float*)d_in[0];
    const float* Wq = (const float*)d_in[1];
    const float* bq = (const float*)d_in[2];
    const float* Wk = (const float*)d_in[3];
    const float* bk = (const float*)d_in[4];
    const float* Wv = (const float*)d_in[5];
    const float* bv = (const float*)d_in[6];
    const float* Wo = (const float*)d_in[7];
    const float* bo = (const float*)d_in[8];
    float* out = (float*)d_out;

    float* ws  = (float*)d_ws;
    float* Qw  = ws;                          // 294912
    float* Kw  = Qw + 294912;                 // 272384 (33 rows + pad)
    float* Vw  = Kw + 272384;                 // 272384
    float* Zt  = Vw + 272384;                 // 270336
    float* Zp  = Zt + 270336;                 // 4 * 786432

    gemm_qkv_split_kernel<<<dim3(12, 32, 4), 256, 0, stream>>>(x, Wq, Wk, Wv, Zp);
    reduce_fl_kernel<<<96, 256, 0, stream>>>(Zp, bq, bk, bv, Qw, Kw, Vw);
    attn_kernel<<<dim3(128, 16), 256, 0, stream>>>(Qw, Kw, Vw, Zt);
    out_gemm_kernel<<<dim3(16, 32), 256, 0, stream>>>(Zt, Wo, bo, out);
}

// Round 10
// 80.491 us; speedup vs baseline: 1.0576x; 1.0576x over previous
//
#include <hip/hip_runtime.h>
#include <math.h>

// ---------------------------------------------------------------------------
// LorentzSelfAttention — MI355X
//
// Degenerate-clamp simplification (verified analytically, passed R1-R9):
//   u_agg_i = C*(W_i + S_i*Q_i),  W_i = sum_j p_ij V_j (unnormalized),
//   S_i = sum_j p_ij alpha_ij = -mink(Q_i, W_i)   [alpha bilinear in V]
//   Y_i = mink_normalize(Q_i + u_agg_i/sum_e), |time|
//   Ztan_i = dist0*C * (2*Y0, Ys),  dist0 = acosh(max(Y0,1+eps))
//
// R10 = R8 config (8 rows/block attn, split-K x2, 32x32 out_gemm) + R9's
// per-pair wins (float2 j-pair loads, S-identity) + reduce_fl 384 blocks.
// R9 lesson: fewer rows/block doubles per-block K/V L2 re-reads — keep 8.
// ---------------------------------------------------------------------------

namespace {

constexpr int Tq = 512;
constexpr int QS = 36;            // padded Q row stride
constexpr int ZPHALF = 786432;    // 1024*768

#define EPSF  1e-6f
#define CINV  3.16227766e7f       // 1/sqrt(1e-15)

__device__ __forceinline__ float facosh(float x) {
    // caller guarantees x >= 1+1e-6
    return __logf(x + __builtin_amdgcn_sqrtf(fmaf(x, x, -1.0f)));
}

// ---------------- Kernel 1: QKV GEMM, split-K x2, 32x64 tiles (R8) ---------
__global__ __launch_bounds__(256) void gemm_qkv_split_kernel(
    const float* __restrict__ x,
    const float* __restrict__ Wq, const float* __restrict__ Wk,
    const float* __restrict__ Wv, float* __restrict__ zpart)
{
    __shared__ float AsT[32][36];     // k-major
    __shared__ float BsT[32][68];

    const int n0 = blockIdx.x * 64;   // 0..704
    const int m0 = blockIdx.y * 32;   // 0..992
    const int kz = blockIdx.z;        // 0/1
    const int t  = threadIdx.x;
    const int tx = t & 15, ty = t >> 4;

    float acc[2][4];
    #pragma unroll
    for (int r = 0; r < 2; ++r)
        #pragma unroll
        for (int c = 0; c < 4; ++c) acc[r][c] = 0.f;

    const int ob  = n0 + (t >> 2);    // B row staged by this thread
    const float* WselB = (ob < 256) ? Wq : (ob < 512 ? Wk : Wv);
    const int obr = ob & 255;
    const int ar  = t >> 3;           // A row 0..31
    const int ac  = (t & 7) * 4;      // k 0..28
    const int bcc = (t & 3) * 8;      // k 0,8,16,24
    const int bcol = t >> 2;          // 0..63

    const int kbeg = kz * 256;
    for (int k0 = kbeg; k0 < kbeg + 256; k0 += 32) {
        const float4 av = *reinterpret_cast<const float4*>(&x[(m0 + ar) * 512 + k0 + ac]);
        AsT[ac + 0][ar] = av.x; AsT[ac + 1][ar] = av.y;
        AsT[ac + 2][ar] = av.z; AsT[ac + 3][ar] = av.w;
        const float4 b0 = *reinterpret_cast<const float4*>(&WselB[obr * 512 + k0 + bcc]);
        const float4 b1 = *reinterpret_cast<const float4*>(&WselB[obr * 512 + k0 + bcc + 4]);
        BsT[bcc + 0][bcol] = b0.x; BsT[bcc + 1][bcol] = b0.y;
        BsT[bcc + 2][bcol] = b0.z; BsT[bcc + 3][bcol] = b0.w;
        BsT[bcc + 4][bcol] = b1.x; BsT[bcc + 5][bcol] = b1.y;
        BsT[bcc + 6][bcol] = b1.z; BsT[bcc + 7][bcol] = b1.w;
        __syncthreads();
        #pragma unroll
        for (int kk = 0; kk < 32; ++kk) {
            const float2 a2 = *reinterpret_cast<const float2*>(&AsT[kk][ty * 2]);
            const float4 b4 = *reinterpret_cast<const float4*>(&BsT[kk][tx * 4]);
            const float ar2[2] = {a2.x, a2.y};
            const float br4[4] = {b4.x, b4.y, b4.z, b4.w};
            #pragma unroll
            for (int r = 0; r < 2; ++r)
                #pragma unroll
                for (int c = 0; c < 4; ++c) acc[r][c] = fmaf(ar2[r], br4[c], acc[r][c]);
        }
        __syncthreads();
    }
    float* zp = zpart + kz * ZPHALF + (m0 + ty * 2) * 768 + n0 + tx * 4;
    #pragma unroll
    for (int r = 0; r < 2; ++r) {
        float4 o; o.x = acc[r][0]; o.y = acc[r][1]; o.z = acc[r][2]; o.w = acc[r][3];
        *reinterpret_cast<float4*>(zp + r * 768) = o;
    }
}

// ---------------- Kernel 2: reduce halves + bias + FL lift (384 blocks) ----
__global__ __launch_bounds__(64) void reduce_fl_kernel(
    const float* __restrict__ zpart,
    const float* __restrict__ bq, const float* __restrict__ bk,
    const float* __restrict__ bv,
    float* __restrict__ Q, float* __restrict__ K, float* __restrict__ V)
{
    const int u = blockIdx.x * 64 + threadIdx.x;    // < 24576
    const int tt = u & 511;
    const int rest = u >> 9;          // 0..47
    const int bh = rest & 15;
    const int which = rest >> 4;      // 0=q 1=k 2=v
    const int b = bh >> 3, h = bh & 7;
    const int row = b * 512 + tt;
    const int col = which * 256 + h * 32;
    const float* z0 = zpart + row * 768 + col;
    const float* z1 = zpart + ZPHALF + row * 768 + col;
    const float* bsel = (which == 0) ? bq : (which == 1 ? bk : bv);

    float zv[32];
    float s2 = 0.f;
    #pragma unroll
    for (int c = 0; c < 8; ++c) {
        const float4 a = *reinterpret_cast<const float4*>(&z0[c * 4]);
        const float4 d = *reinterpret_cast<const float4*>(&z1[c * 4]);
        const float4 bb = *reinterpret_cast<const float4*>(&bsel[h * 32 + c * 4]);
        zv[c*4+0] = a.x + d.x + bb.x; zv[c*4+1] = a.y + d.y + bb.y;
        zv[c*4+2] = a.z + d.z + bb.z; zv[c*4+3] = a.w + d.w + bb.w;
    }
    #pragma unroll
    for (int k = 0; k < 32; ++k) s2 = fmaf(zv[k], zv[k], s2);

    const float rr = __builtin_amdgcn_sqrtf(s2);
    const float rs = fminf(fmaxf(rr, 1e-12f), 18.0f);
    const float e  = __expf(rs);
    const float ei = __builtin_amdgcn_rcpf(e);
    const float ch = 0.5f * (e + ei);
    float sc = 0.5f * (e - ei) / rs;
    if (rs < 1e-3f) sc = fmaf(rs * rs, 1.0f / 6.0f, 1.0f);
    float y0 = ch;
    float ys[32];
    float mink = -y0 * y0;
    #pragma unroll
    for (int k = 0; k < 32; ++k) { ys[k] = sc * zv[k]; mink = fmaf(ys[k], ys[k], mink); }
    const float inv = __builtin_amdgcn_rsqf(fmaxf(fabsf(mink), 1e-15f));
    y0 = fabsf(y0 * inv);

    if (which == 0) {
        float* qp = Q + (bh * Tq + tt) * QS;
        #pragma unroll
        for (int k = 0; k < 32; ++k) qp[k] = ys[k] * inv;
        qp[32] = y0; qp[33] = 0.f; qp[34] = 0.f; qp[35] = 0.f;
    } else {
        float* p = ((which == 1) ? K : V) + bh * 33 * Tq + tt;
        p[0] = y0;
        #pragma unroll
        for (int k = 0; k < 32; ++k) p[(k + 1) * Tq] = ys[k] * inv;
    }
}

// ---------------- Kernel 3: attention, 8 rows/block, j-pair threads --------
// 256 threads, grid (64,16). Thread t owns columns {2t, 2t+1} (float2 loads).
__global__ __launch_bounds__(256) void attn_kernel(
    const float* __restrict__ Q, const float* __restrict__ K,
    const float* __restrict__ V, float* __restrict__ Ztan)
{
    __shared__ float sQ[8][36];       // [0..31]=spatial, [32]=time
    __shared__ float sBig[8 * 512];   // p matrix; P4 partials alias
    __shared__ float sSe[8][4];       // per-wave sum_e partials
    __shared__ float sW[8][33];

    float (*sP)[512] = reinterpret_cast<float(*)[512]>(sBig);
    float (*part)[8][36] = reinterpret_cast<float(*)[8][36]>(sBig); // [g][sub][36]

    const int bh = blockIdx.y;
    const int i0 = blockIdx.x * 8;
    const int t  = threadIdx.x;       // 0..255
    const int lane = t & 63, wv = t >> 6;

    const float* Qb = Q + (bh * Tq + i0) * QS;
    const float* Kb = K + bh * 33 * Tq;
    const float* Vb = V + bh * 33 * Tq;

    for (int idx = t; idx < 8 * QS; idx += 256)
        sQ[idx / QS][idx % QS] = Qb[idx];
    __syncthreads();

    // ---- P1: p = exp(-d^2)*dd into LDS; row sum_e in regs -----------------
    float se[8];
    #pragma unroll
    for (int i = 0; i < 8; ++i) se[i] = 0.f;
    {
        const int j0 = 2 * t;
        float aK[8][2], aV[8][2];
        #pragma unroll
        for (int i = 0; i < 8; ++i) {
            aK[i][0] = aK[i][1] = 0.f; aV[i][0] = aV[i][1] = 0.f;
        }
        #pragma unroll 1
        for (int ch = 0; ch < 4; ++ch) {
            float2 ks[8], vs[8];
            #pragma unroll
            for (int k = 0; k < 8; ++k) {
                ks[k] = *reinterpret_cast<const float2*>(&Kb[(ch * 8 + k + 1) * Tq + j0]);
                vs[k] = *reinterpret_cast<const float2*>(&Vb[(ch * 8 + k + 1) * Tq + j0]);
            }
            #pragma unroll
            for (int i = 0; i < 8; ++i) {
                const float4 qa = *reinterpret_cast<const float4*>(&sQ[i][ch * 8]);
                const float4 qb = *reinterpret_cast<const float4*>(&sQ[i][ch * 8 + 4]);
                const float qv[8] = {qa.x, qa.y, qa.z, qa.w, qb.x, qb.y, qb.z, qb.w};
                float k0a = aK[i][0], k1a = aK[i][1];
                float v0a = aV[i][0], v1a = aV[i][1];
                #pragma unroll
                for (int k = 0; k < 8; ++k) {
                    k0a = fmaf(qv[k], ks[k].x, k0a);
                    k1a = fmaf(qv[k], ks[k].y, k1a);
                    v0a = fmaf(qv[k], vs[k].x, v0a);
                    v1a = fmaf(qv[k], vs[k].y, v1a);
                }
                aK[i][0] = k0a; aK[i][1] = k1a; aV[i][0] = v0a; aV[i][1] = v1a;
            }
        }
        const float2 k0v = *reinterpret_cast<const float2*>(&Kb[j0]);
        const float2 v0v = *reinterpret_cast<const float2*>(&Vb[j0]);
        #pragma unroll
        for (int i = 0; i < 8; ++i) {
            const float q0 = sQ[i][32];
            const float ip0 = fmaf(q0, k0v.x, -aK[i][0]);
            const float ip1 = fmaf(q0, k0v.y, -aK[i][1]);
            const float d0 = facosh(fmaxf(ip0, 1.0f + EPSF));
            const float d1 = facosh(fmaxf(ip1, 1.0f + EPSF));
            const float al0 = fmaxf(fmaf(q0, v0v.x, -aV[i][0]), 1.0f + EPSF);
            const float al1 = fmaxf(fmaf(q0, v0v.y, -aV[i][1]), 1.0f + EPSF);
            const float e0 = __expf(-d0 * d0);
            const float e1 = __expf(-d1 * d1);
            float2 p; p.x = e0 * facosh(al0); p.y = e1 * facosh(al1);
            *reinterpret_cast<float2*>(&sP[i][j0]) = p;
            se[i] += e0 + e1;
        }
    }
    #pragma unroll
    for (int i = 0; i < 8; ++i) {
        float a = se[i];
        #pragma unroll
        for (int off = 32; off > 0; off >>= 1) a += __shfl_xor(a, off, 64);
        if (lane == 0) sSe[i][wv] = a;
    }
    __syncthreads();

    // ---- P4: Wraw[i][a] = sum_j p_ij * V[a][j] (R8 structure) -------------
    {
        const int jl = t & 31, g = t >> 5;
        const int rg = g & 1, ag = g >> 1;
        const int abase = ag * 8;         // 0,8,16,24; +8 = 32 in range
        const int ibase = rg * 4;
        float acc[4][9];
        #pragma unroll
        for (int il = 0; il < 4; ++il)
            #pragma unroll
            for (int al = 0; al < 9; ++al) acc[il][al] = 0.f;

        #pragma unroll 1
        for (int it = 0; it < 8; ++it) {
            const int jb = it * 64 + jl * 2;
            float2 v2[9];
            #pragma unroll
            for (int al = 0; al < 9; ++al)
                v2[al] = *reinterpret_cast<const float2*>(&Vb[(abase + al) * Tq + jb]);
            #pragma unroll
            for (int il = 0; il < 4; ++il) {
                const float2 w2 = *reinterpret_cast<const float2*>(&sP[ibase + il][jb]);
                #pragma unroll
                for (int al = 0; al < 9; ++al)
                    acc[il][al] = fmaf(w2.y, v2[al].y, fmaf(w2.x, v2[al].x, acc[il][al]));
            }
        }
        #pragma unroll
        for (int il = 0; il < 4; ++il)
            #pragma unroll
            for (int al = 0; al < 9; ++al) {
                float v = acc[il][al];
                v += __shfl_xor(v, 1, 64);
                v += __shfl_xor(v, 2, 64);
                acc[il][al] = v;
            }
        __syncthreads();   // all sP reads complete before part overwrites
        if ((jl & 3) == 0) {
            const int sub = jl >> 2;
            #pragma unroll
            for (int il = 0; il < 4; ++il)
                #pragma unroll
                for (int al = 0; al < 9; ++al)
                    part[g][sub][il * 9 + al] = acc[il][al];
        }
    }
    __syncthreads();

    // ---- stage 2: fold 8 partials per (i,a) -------------------------------
    for (int task = t; task < 8 * 33; task += 256) {
        const int i = task / 33, a = task - i * 33;
        int ag2 = a >> 3; if (ag2 > 3) ag2 = 3;
        const int al = a - ag2 * 8;
        const int g2 = ag2 * 2 + (i >> 2);
        const int idx = (i & 3) * 9 + al;
        float s = 0.f;
        #pragma unroll
        for (int sub = 0; sub < 8; ++sub) s += part[g2][sub][idx];
        sW[i][a] = s;
    }
    __syncthreads();

    // ---- P5: S via Minkowski identity; normalize; exp_map; origin log -----
    if (t < 8) {
        const int i = t;
        const float seT = sSe[i][0] + sSe[i][1] + sSe[i][2] + sSe[i][3];
        const float q0 = sQ[i][32];
        // S_raw = -mink(Q, Wraw) = q0*W0 - sum_s qs*Ws
        float dot = 0.f;
        #pragma unroll
        for (int a = 1; a < 33; ++a) dot = fmaf(sQ[i][a - 1], sW[i][a], dot);
        const float S = q0 * sW[i][0] - dot;
        const float cs = CINV * __builtin_amdgcn_rcpf(seT);
        const float y0 = fmaf(cs, fmaf(S, q0, sW[i][0]), q0);
        float mink = -y0 * y0;
        float yv[32];
        #pragma unroll
        for (int a = 1; a < 33; ++a) {
            const float qa = sQ[i][a - 1];
            const float ya = fmaf(cs, fmaf(S, qa, sW[i][a]), qa);
            yv[a - 1] = ya;
            mink = fmaf(ya, ya, mink);
        }
        const float inv = __builtin_amdgcn_rsqf(fmaxf(fabsf(mink), 1e-15f));
        const float Y0 = fabsf(y0 * inv);
        const float dist0 = facosh(fmaxf(Y0, 1.0f + EPSF));
        const float coef = dist0 * CINV;
        const int b = bh >> 3, h = bh & 7;
        float* zp = Ztan + ((b * Tq + (i0 + i)) * 264) + h * 33;
        zp[0] = coef * (2.0f * Y0);
        #pragma unroll
        for (int a = 1; a < 33; ++a) zp[a] = coef * (yv[a - 1] * inv);
    }
}

// ---------------- Kernel 4: Z = Ztan(1024x264) @ Wo^T + bo, 32x32 (R8) -----
__global__ __launch_bounds__(256) void out_gemm_kernel(
    const float* __restrict__ Ztan, const float* __restrict__ Wo,
    const float* __restrict__ bo, float* __restrict__ out)
{
    __shared__ float AsT[8][36];
    __shared__ float BsT[8][36];
    const int n0 = blockIdx.x * 32;
    const int m0 = blockIdx.y * 32;
    const int t  = threadIdx.x;
    const int tx = t & 15, ty = t >> 4;
    const int ar = t >> 3, ac = t & 7;

    float acc[2][2];
    acc[0][0] = acc[0][1] = acc[1][0] = acc[1][1] = 0.f;

    for (int k0 = 0; k0 < 264; k0 += 8) {
        AsT[ac][ar] = Ztan[(m0 + ar) * 264 + k0 + ac];
        BsT[ac][ar] = Wo[(n0 + ar) * 264 + k0 + ac];
        __syncthreads();
        #pragma unroll
        for (int kk = 0; kk < 8; ++kk) {
            const float2 a2 = *reinterpret_cast<const float2*>(&AsT[kk][ty * 2]);
            const float2 b2 = *reinterpret_cast<const float2*>(&BsT[kk][tx * 2]);
            acc[0][0] = fmaf(a2.x, b2.x, acc[0][0]);
            acc[0][1] = fmaf(a2.x, b2.y, acc[0][1]);
            acc[1][0] = fmaf(a2.y, b2.x, acc[1][0]);
            acc[1][1] = fmaf(a2.y, b2.y, acc[1][1]);
        }
        __syncthreads();
    }
    #pragma unroll
    for (int c = 0; c < 2; ++c) {
        const int o = n0 + tx * 2 + c;
        const float bias = bo[o];
        #pragma unroll
        for (int r = 0; r < 2; ++r)
            out[(m0 + ty * 2 + r) * 512 + o] = acc[r][c] + bias;
    }
}

} // namespace

// ---------------------------------------------------------------------------
extern "C" void kernel_launch(void* const* d_in, const int* in_sizes, int n_in,
                              void* d_out, int out_size, void* d_ws, size_t ws_size,
                              hipStream_t stream)
{
    const float* x  = (const float*)d_in[0];
    const float* Wq = (const float*)d_in[1];
    const float* bq = (const float*)d_in[2];
    const float* Wk = (const float*)d_in[3];
    const float* bk = (const float*)d_in[4];
    const float* Wv = (const float*)d_in[5];
    const float* bv = (const float*)d_in[6];
    const float* Wo = (const float*)d_in[7];
    const float* bo = (const float*)d_in[8];
    float* out = (float*)d_out;

    float* ws  = (float*)d_ws;
    float* Qw  = ws;                          // 294912
    float* Kw  = Qw + 294912;                 // 272384 (33 rows + pad)
    float* Vw  = Kw + 272384;                 // 272384
    float* Zt  = Vw + 272384;                 // 270336
    float* Zp  = Zt + 270336;                 // 2 * 786432

    gemm_qkv_split_kernel<<<dim3(12, 32, 2), 256, 0, stream>>>(x, Wq, Wk, Wv, Zp);
    reduce_fl_kernel<<<384, 64, 0, stream>>>(Zp, bq, bk, bv, Qw, Kw, Vw);
    attn_kernel<<<dim3(64, 16), 256, 0, stream>>>(Qw, Kw, Vw, Zt);
    out_gemm_kernel<<<dim3(16, 32), 256, 0, stream>>>(Zt, Wo, bo, out);
}